// Round 9
// baseline (142.437 us; speedup 1.0000x reference)
//
#include <hip/hip_runtime.h>
#include <math.h>

#define NBATCH 8192
#define NIN 64
#define NOUT 64
#define NG 17

typedef float f32x4 __attribute__((ext_vector_type(4)));

// d_out layout (flat, f32): output[8192*64] | edge[8192*64*64] | basis[8192*64*17]
#define OUT_ELEMS   (NBATCH * NOUT)
#define EDGE_ELEMS  (NBATCH * NIN * NOUT)
#define BASIS_ELEMS (NBATCH * NIN * NG)
#define OUT_TOTAL   (OUT_ELEMS + EDGE_ELEMS + BASIS_ELEMS)   // 42,991,616 floats
#define WT_FLOATS   (NIN * NG * NOUT)                        // 69,632
#define WT_BYTES    (WT_FLOATS * sizeof(float))

__global__ void kan_transpose_w(const float* __restrict__ W, float* __restrict__ Wt) {
    int idx = blockIdx.x * blockDim.x + threadIdx.x;
    if (idx >= NIN * NOUT * NG) return;
    int i   = idx / (NOUT * NG);
    int rem = idx - i * (NOUT * NG);
    int o   = rem / NG;
    int g   = rem - o * NG;
    Wt[(i * NG + g) * NOUT + o] = W[idx];
}

// DIAGNOSTIC build: grid = 2048 * 4; rep = blockIdx.x>>11 selects output target.
// rep 0 -> real d_out; rep 1..n_ws_reps -> disjoint d_ws regions (real, distinct
// store traffic); higher reps (if ws too small) -> duplicate-write d_out.
__global__ __launch_bounds__(256) void kan_kernel(
    const float* __restrict__ x,
    const float* __restrict__ scale,
    const float* __restrict__ Wt,
    const float* __restrict__ bias,
    float* __restrict__ out,
    float* __restrict__ edge,
    float* __restrict__ basis,
    float* __restrict__ wsrep,   // replica base (after Wt region)
    int n_ws_reps)
{
    const int wave = threadIdx.x >> 6;
    const int lane = threadIdx.x & 63;
    const int rep  = blockIdx.x >> 11;
    const int bblk = blockIdx.x & 2047;
    const int b = bblk * 4 + wave;

    float *o_, *e_, *b_;
    if (rep == 0 || rep > n_ws_reps) {
        o_ = out; e_ = edge; b_ = basis;
    } else {
        float* base = wsrep + (size_t)(rep - 1) * OUT_TOTAL;
        o_ = base; e_ = base + OUT_ELEMS; b_ = base + OUT_ELEMS + EDGE_ELEMS;
    }

    __shared__ float s_silu[4][64];
    __shared__ float s_t[4][64];
    __shared__ int   s_g0[4][64];

    // ---- phase 1: per-input-feature precompute (lane == i) ----
    {
        float xv  = x[b * NIN + lane];
        float sig = 1.0f / (1.0f + __expf(-xv));
        s_silu[wave][lane] = xv * sig;
        float u   = (xv + 2.5f) * 3.2f;      // spacing = 5/16
        float g0f = floorf(u);
        s_t[wave][lane]  = u - g0f;
        s_g0[wave][lane] = (int)g0f;
    }
    __syncthreads();

    // ---- phase 2: basis writes, float4 (1088 floats = 272 f4) ----
    {
        float* brow = b_ + (size_t)b * (NIN * NG);
        #pragma unroll
        for (int k = 0; k < 4; ++k) {
            int p0 = (k * 64 + lane) * 4;
            f32x4 v;
            #pragma unroll
            for (int e = 0; e < 4; ++e) {
                int p = p0 + e;
                int i = (int)((unsigned)p / 17u);
                int g = p - i * 17;
                int   g0 = s_g0[wave][i];
                float t  = s_t[wave][i];
                v[e] = (g == g0) ? (1.0f - t) : ((g == g0 + 1) ? t : 0.0f);
            }
            *(f32x4*)(brow + p0) = v;
        }
        if (lane < 16) {
            int p0 = (256 + lane) * 4;
            f32x4 v;
            #pragma unroll
            for (int e = 0; e < 4; ++e) {
                int p = p0 + e;
                int i = (int)((unsigned)p / 17u);
                int g = p - i * 17;
                int   g0 = s_g0[wave][i];
                float t  = s_t[wave][i];
                v[e] = (g == g0) ? (1.0f - t) : ((g == g0 + 1) ? t : 0.0f);
            }
            *(f32x4*)(brow + p0) = v;
        }
    }

    // ---- phase 3: edge outputs (float4) + per-row reduction ----
    f32x4 acc = {0.f, 0.f, 0.f, 0.f};
    float* erow = e_ + (size_t)b * (NIN * NOUT);
    const int iq = lane >> 4;
    const int o  = (lane & 15) * 4;
    #pragma unroll 4
    for (int ib = 0; ib < NIN; ib += 4) {
        int   i  = ib + iq;
        float sl = s_silu[wave][i];
        float t  = s_t[wave][i];
        int   g0 = s_g0[wave][i];
        f32x4 sc = *(const f32x4*)(scale + i * NOUT + o);
        f32x4 w0 = {0.f, 0.f, 0.f, 0.f};
        f32x4 w1 = {0.f, 0.f, 0.f, 0.f};
        if ((unsigned)g0       < (unsigned)NG) w0 = *(const f32x4*)(Wt + (i * NG + g0)     * NOUT + o);
        if ((unsigned)(g0 + 1) < (unsigned)NG) w1 = *(const f32x4*)(Wt + (i * NG + g0 + 1) * NOUT + o);
        float mt = 1.0f - t;
        f32x4 v = sl * sc + mt * w0 + t * w1;
        *(f32x4*)(erow + i * NOUT + o) = v;
        acc += v;
    }
    #pragma unroll
    for (int e = 0; e < 4; ++e) {
        float a = acc[e];
        a += __shfl_xor(a, 16);
        a += __shfl_xor(a, 32);
        acc[e] = a;
    }
    if (lane < 16) {
        f32x4 bi = *(const f32x4*)(bias + lane * 4);
        f32x4 r = acc * 0.125f + bi;
        *(f32x4*)(o_ + (size_t)b * NOUT + lane * 4) = r;
    }
}

extern "C" void kernel_launch(void* const* d_in, const int* in_sizes, int n_in,
                              void* d_out, int out_size, void* d_ws, size_t ws_size,
                              hipStream_t stream) {
    const float* x     = (const float*)d_in[0];
    const float* scale = (const float*)d_in[1];
    const float* W     = (const float*)d_in[2];
    const float* bias  = (const float*)d_in[3];

    float* out   = (float*)d_out;
    float* edge  = out + OUT_ELEMS;
    float* basis = edge + EDGE_ELEMS;

    float* Wt    = (float*)d_ws;
    float* wsrep = Wt + WT_FLOATS;

    // how many full output replicas fit in ws after the Wt region?
    int n_ws_reps = 0;
    size_t avail = (ws_size > WT_BYTES) ? (ws_size - WT_BYTES) : 0;
    while (n_ws_reps < 3 &&
           (size_t)(n_ws_reps + 1) * (size_t)OUT_TOTAL * sizeof(float) <= avail)
        ++n_ws_reps;

    const int n = NIN * NOUT * NG;
    if (ws_size >= WT_BYTES) {
        kan_transpose_w<<<(n + 255) / 256, 256, 0, stream>>>(W, Wt);
        kan_kernel<<<dim3(2048 * 4), dim3(256), 0, stream>>>(
            x, scale, Wt, bias, out, edge, basis, wsrep, n_ws_reps);
    }
}

// Round 10
// 39.270 us; speedup vs baseline: 3.6271x; 3.6271x over previous
//
#include <hip/hip_runtime.h>
#include <math.h>

#define NBATCH 8192
#define NIN 64
#define NOUT 64
#define NG 17

typedef float f32x4 __attribute__((ext_vector_type(4)));

// d_out layout (flat, f32): output[8192*64] | edge[8192*64*64] | basis[8192*64*17]
#define OUT_ELEMS   (NBATCH * NOUT)
#define EDGE_ELEMS  (NBATCH * NIN * NOUT)
#define WT_FLOATS   (NIN * NG * NOUT)
#define WT_BYTES    (WT_FLOATS * sizeof(float))

__global__ void kan_transpose_w(const float* __restrict__ W, float* __restrict__ Wt) {
    int idx = blockIdx.x * blockDim.x + threadIdx.x;
    if (idx >= NIN * NOUT * NG) return;
    int i   = idx / (NOUT * NG);
    int rem = idx - i * (NOUT * NG);
    int o   = rem / NG;
    int g   = rem - o * NG;
    Wt[(i * NG + g) * NOUT + o] = W[idx];
}

// 8 waves per block = 8 batch rows; scale staged in LDS once per block.
__global__ __launch_bounds__(512) void kan_kernel(
    const float* __restrict__ x,      // [B, 64]
    const float* __restrict__ scale,  // [64, 64]
    const float* __restrict__ Wt,     // [64, 17, 64] (transposed)
    const float* __restrict__ bias,   // [64]
    float* __restrict__ out,          // [B, 64]
    float* __restrict__ edge,         // [B, 64, 64]
    float* __restrict__ basis)        // [B, 64, 17]
{
    const int tid  = threadIdx.x;
    const int wave = tid >> 6;
    const int lane = tid & 63;
    const int b = blockIdx.x * 8 + wave;

    __shared__ float s_scale[NIN * NOUT];   // 16 KB
    __shared__ float s_silu[8][64];
    __shared__ float s_t[8][64];
    __shared__ int   s_g0[8][64];

    // ---- stage scale into LDS (1024 f32x4, 512 threads x 2) ----
    {
        const f32x4* s4 = (const f32x4*)scale;
        f32x4* d4 = (f32x4*)s_scale;
        d4[tid]       = s4[tid];
        d4[tid + 512] = s4[tid + 512];
    }

    // ---- phase 1: per-input-feature precompute (lane == i) ----
    {
        float xv  = x[b * NIN + lane];
        float sig = 1.0f / (1.0f + __expf(-xv));
        s_silu[wave][lane] = xv * sig;
        float u   = (xv + 2.5f) * 3.2f;      // spacing = 5/16 exact
        float g0f = floorf(u);
        s_t[wave][lane]  = u - g0f;
        s_g0[wave][lane] = (int)g0f;
    }
    __syncthreads();

    // ---- phase 2: basis writes, float4 (1088 floats = 272 f4 per row) ----
    {
        float* brow = basis + (size_t)b * (NIN * NG);
        #pragma unroll
        for (int k = 0; k < 4; ++k) {
            int p0 = (k * 64 + lane) * 4;
            f32x4 v;
            #pragma unroll
            for (int e = 0; e < 4; ++e) {
                int p = p0 + e;
                int i = (int)((unsigned)p / 17u);
                int g = p - i * 17;
                int   g0 = s_g0[wave][i];
                float t  = s_t[wave][i];
                v[e] = (g == g0) ? (1.0f - t) : ((g == g0 + 1) ? t : 0.0f);
            }
            *(f32x4*)(brow + p0) = v;
        }
        if (lane < 16) {
            int p0 = (256 + lane) * 4;
            f32x4 v;
            #pragma unroll
            for (int e = 0; e < 4; ++e) {
                int p = p0 + e;
                int i = (int)((unsigned)p / 17u);
                int g = p - i * 17;
                int   g0 = s_g0[wave][i];
                float t  = s_t[wave][i];
                v[e] = (g == g0) ? (1.0f - t) : ((g == g0 + 1) ? t : 0.0f);
            }
            *(f32x4*)(brow + p0) = v;
        }
    }

    // ---- phase 3: edge outputs (float4) + per-row reduction ----
    // quarter iq = lane>>4 owns input i = ib+iq; o = (lane&15)*4.
    f32x4 acc = {0.f, 0.f, 0.f, 0.f};
    float* erow = edge + (size_t)b * (NIN * NOUT);
    const int iq = lane >> 4;
    const int o  = (lane & 15) * 4;
    #pragma unroll 4
    for (int ib = 0; ib < NIN; ib += 4) {
        int   i  = ib + iq;
        float sl = s_silu[wave][i];
        float t  = s_t[wave][i];
        int   g0 = s_g0[wave][i];
        f32x4 sc = *(const f32x4*)(s_scale + i * NOUT + o);   // LDS, not L2
        f32x4 w0 = {0.f, 0.f, 0.f, 0.f};
        f32x4 w1 = {0.f, 0.f, 0.f, 0.f};
        if ((unsigned)g0       < (unsigned)NG) w0 = *(const f32x4*)(Wt + (i * NG + g0)     * NOUT + o);
        if ((unsigned)(g0 + 1) < (unsigned)NG) w1 = *(const f32x4*)(Wt + (i * NG + g0 + 1) * NOUT + o);
        float mt = 1.0f - t;
        f32x4 v = sl * sc + mt * w0 + t * w1;
        *(f32x4*)(erow + i * NOUT + o) = v;
        acc += v;
    }
    #pragma unroll
    for (int e = 0; e < 4; ++e) {
        float a = acc[e];
        a += __shfl_xor(a, 16);
        a += __shfl_xor(a, 32);
        acc[e] = a;
    }
    if (lane < 16) {
        f32x4 bi = *(const f32x4*)(bias + lane * 4);
        f32x4 r = acc * 0.125f + bi;   // 1/sqrt(64) = 0.125 exact
        *(f32x4*)(out + (size_t)b * NOUT + lane * 4) = r;
    }
}

extern "C" void kernel_launch(void* const* d_in, const int* in_sizes, int n_in,
                              void* d_out, int out_size, void* d_ws, size_t ws_size,
                              hipStream_t stream) {
    const float* x     = (const float*)d_in[0];
    const float* scale = (const float*)d_in[1];
    const float* W     = (const float*)d_in[2];
    const float* bias  = (const float*)d_in[3];

    float* out   = (float*)d_out;
    float* edge  = out + OUT_ELEMS;
    float* basis = edge + EDGE_ELEMS;

    float* Wt = (float*)d_ws;
    const int n = NIN * NOUT * NG;
    if (ws_size >= WT_BYTES) {
        kan_transpose_w<<<(n + 255) / 256, 256, 0, stream>>>(W, Wt);
        kan_kernel<<<dim3(NBATCH / 8), dim3(512), 0, stream>>>(x, scale, Wt, bias, out, edge, basis);
    }
}